// Round 1
// baseline (908.389 us; speedup 1.0000x reference)
//
#include <hip/hip_runtime.h>

#define N_NODES 100000
#define N_EDGES 1600000
#define DIM 64
#define NEG_SLOPE 0.01f

// ---------------- histogram of dst (in-degree, excl self-loop) ----------------
__global__ void hist_kernel(const int* __restrict__ dst, int* __restrict__ counts) {
    int e = blockIdx.x * blockDim.x + threadIdx.x;
    if (e < N_EDGES) atomicAdd(&counts[dst[e]], 1);
}

// ---------------- 3-phase exclusive scan over counts[N] ----------------
__global__ void scan_partial(const int* __restrict__ counts, int* __restrict__ bsums) {
    __shared__ int sm[1024];
    int i = blockIdx.x * 1024 + threadIdx.x;
    int v = (i < N_NODES) ? counts[i] : 0;
    sm[threadIdx.x] = v;
    __syncthreads();
    for (int s = 512; s > 0; s >>= 1) {
        if (threadIdx.x < s) sm[threadIdx.x] += sm[threadIdx.x + s];
        __syncthreads();
    }
    if (threadIdx.x == 0) bsums[blockIdx.x] = sm[0];
}

__global__ void scan_bsums(int* __restrict__ bsums, int nb) {
    __shared__ int sm[128];
    if ((int)threadIdx.x < nb) sm[threadIdx.x] = bsums[threadIdx.x];
    __syncthreads();
    if (threadIdx.x == 0) {
        int run = 0;
        for (int b = 0; b < nb; ++b) { int t = sm[b]; sm[b] = run; run += t; }
    }
    __syncthreads();
    if ((int)threadIdx.x < nb) bsums[threadIdx.x] = sm[threadIdx.x];
}

__global__ void scan_final(const int* __restrict__ counts, const int* __restrict__ bsums,
                           int* __restrict__ offsets, float* __restrict__ dinv) {
    __shared__ int sm[1024];
    int i = blockIdx.x * 1024 + threadIdx.x;
    int v = (i < N_NODES) ? counts[i] : 0;
    sm[threadIdx.x] = v;
    __syncthreads();
    for (int s = 1; s < 1024; s <<= 1) {
        int add = ((int)threadIdx.x >= s) ? sm[threadIdx.x - s] : 0;
        __syncthreads();
        sm[threadIdx.x] += add;
        __syncthreads();
    }
    int incl = sm[threadIdx.x];
    if (i < N_NODES) {
        offsets[i] = bsums[blockIdx.x] + (incl - v);
        dinv[i] = rsqrtf((float)(v + 1));   // deg includes self-loop
    }
    if (i == 0) offsets[N_NODES] = N_EDGES;
}

// ---------------- CSR fill: group edges by dst, precompute coef ----------------
__global__ void fill_csr(const int* __restrict__ src, const int* __restrict__ dst,
                         const int* __restrict__ offsets, int* __restrict__ cursor,
                         const float* __restrict__ dinv, int2* __restrict__ csr) {
    int e = blockIdx.x * blockDim.x + threadIdx.x;
    if (e >= N_EDGES) return;
    int s = src[e], d = dst[e];
    int pos = offsets[d] + atomicAdd(&cursor[d], 1);
    float c = dinv[s] * dinv[d];
    csr[pos] = make_int2(s, __float_as_int(c));
}

// ---------------- fp32 matmul: T[i,:] = X[i,:] @ W (64x64) ----------------
// Block = 256 threads handles 64 rows. In-place safe (stages its 64 rows to LDS
// behind a barrier before any store).
__global__ __launch_bounds__(256) void mm_kernel(const float* X, const float* __restrict__ W,
                                                 float* T) {
    __shared__ float xs[64][68];   // +4 pad: r-groups land on distinct banks
    __shared__ float ws[64][64];
    const int t = threadIdx.x;
    const int rbase = blockIdx.x * 64;

    const float4* Wv = (const float4*)W;
    for (int i = t; i < 1024; i += 256)
        ((float4*)&ws[0][0])[i] = Wv[i];

    for (int i = t; i < 1024; i += 256) {
        int r = i >> 4, kb = i & 15;
        int row = rbase + r;
        float4 xv = make_float4(0.f, 0.f, 0.f, 0.f);
        if (row < N_NODES) xv = *(const float4*)(X + row * DIM + kb * 4);
        *(float4*)&xs[r][kb * 4] = xv;
    }
    __syncthreads();

    const int c4 = (t & 15) * 4;
    const int r0 = t >> 4;
    float4 a0 = make_float4(0.f, 0.f, 0.f, 0.f), a1 = a0, a2 = a0, a3 = a0;

#pragma unroll 4
    for (int kb = 0; kb < 16; ++kb) {
        float x0[4], x1[4], x2[4], x3[4];
        *(float4*)x0 = *(const float4*)&xs[r0][kb * 4];
        *(float4*)x1 = *(const float4*)&xs[r0 + 16][kb * 4];
        *(float4*)x2 = *(const float4*)&xs[r0 + 32][kb * 4];
        *(float4*)x3 = *(const float4*)&xs[r0 + 48][kb * 4];
#pragma unroll
        for (int j = 0; j < 4; ++j) {
            float4 wv = *(const float4*)&ws[kb * 4 + j][c4];
            a0.x = fmaf(x0[j], wv.x, a0.x); a0.y = fmaf(x0[j], wv.y, a0.y);
            a0.z = fmaf(x0[j], wv.z, a0.z); a0.w = fmaf(x0[j], wv.w, a0.w);
            a1.x = fmaf(x1[j], wv.x, a1.x); a1.y = fmaf(x1[j], wv.y, a1.y);
            a1.z = fmaf(x1[j], wv.z, a1.z); a1.w = fmaf(x1[j], wv.w, a1.w);
            a2.x = fmaf(x2[j], wv.x, a2.x); a2.y = fmaf(x2[j], wv.y, a2.y);
            a2.z = fmaf(x2[j], wv.z, a2.z); a2.w = fmaf(x2[j], wv.w, a2.w);
            a3.x = fmaf(x3[j], wv.x, a3.x); a3.y = fmaf(x3[j], wv.y, a3.y);
            a3.z = fmaf(x3[j], wv.z, a3.z); a3.w = fmaf(x3[j], wv.w, a3.w);
        }
    }

    int row;
    row = rbase + r0;      if (row < N_NODES) *(float4*)(T + row * DIM + c4) = a0;
    row = rbase + r0 + 16; if (row < N_NODES) *(float4*)(T + row * DIM + c4) = a1;
    row = rbase + r0 + 32; if (row < N_NODES) *(float4*)(T + row * DIM + c4) = a2;
    row = rbase + r0 + 48; if (row < N_NODES) *(float4*)(T + row * DIM + c4) = a3;
}

// ---------------- aggregate: wave per node, lane per feature ----------------
__global__ __launch_bounds__(256) void agg_kernel(const float* __restrict__ T,
                                                  const int2* __restrict__ csr,
                                                  const int* __restrict__ offsets,
                                                  const float* __restrict__ dinv,
                                                  const float* __restrict__ bias,
                                                  float* __restrict__ out) {
    int wid = (blockIdx.x * 256 + threadIdx.x) >> 6;   // node id
    int lane = threadIdx.x & 63;
    if (wid >= N_NODES) return;
    float di = dinv[wid];
    float acc = di * di * T[wid * DIM + lane];          // self-loop term
    int beg = offsets[wid], end = offsets[wid + 1];
    for (int e = beg; e < end; ++e) {
        int2 p = csr[e];
        acc = fmaf(__int_as_float(p.y), T[p.x * DIM + lane], acc);
    }
    float v = acc + bias[lane];
    out[wid * DIM + lane] = (v >= 0.f) ? v : NEG_SLOPE * v;
}

extern "C" void kernel_launch(void* const* d_in, const int* in_sizes, int n_in,
                              void* d_out, int out_size, void* d_ws, size_t ws_size,
                              hipStream_t stream) {
    const float* x = (const float*)d_in[0];
    const int* ei = (const int*)d_in[1];
    const int* src = ei;
    const int* dst = ei + N_EDGES;
    const float* W[4] = {(const float*)d_in[2], (const float*)d_in[4],
                         (const float*)d_in[6], (const float*)d_in[8]};
    const float* b[4] = {(const float*)d_in[3], (const float*)d_in[5],
                         (const float*)d_in[7], (const float*)d_in[9]};
    float* out = (float*)d_out;

    char* ws = (char*)d_ws;
    size_t off = 0;
    auto alloc = [&](size_t bytes) -> void* {
        void* p = ws + off;
        off = (off + bytes + 255) & ~(size_t)255;
        return p;
    };
    float* A      = (float*)alloc((size_t)N_NODES * DIM * sizeof(float));
    int2*  csr    = (int2*)alloc((size_t)N_EDGES * sizeof(int2));
    int*   counts = (int*)alloc((size_t)N_NODES * sizeof(int));
    int*   cursor = (int*)alloc((size_t)N_NODES * sizeof(int));
    int*   offsets= (int*)alloc((size_t)(N_NODES + 1) * sizeof(int));
    float* dinv   = (float*)alloc((size_t)N_NODES * sizeof(float));
    int*   bsums  = (int*)alloc(128 * sizeof(int));

    const int NB = (N_NODES + 1023) / 1024;   // 98

    hipMemsetAsync(counts, 0, (size_t)N_NODES * sizeof(int), stream);
    hipMemsetAsync(cursor, 0, (size_t)N_NODES * sizeof(int), stream);

    hist_kernel<<<(N_EDGES + 255) / 256, 256, 0, stream>>>(dst, counts);
    scan_partial<<<NB, 1024, 0, stream>>>(counts, bsums);
    scan_bsums<<<1, 128, 0, stream>>>(bsums, NB);
    scan_final<<<NB, 1024, 0, stream>>>(counts, bsums, offsets, dinv);
    fill_csr<<<(N_EDGES + 255) / 256, 256, 0, stream>>>(src, dst, offsets, cursor, dinv, csr);

    const int MM_GRID  = (N_NODES + 63) / 64;          // 1563
    const int AGG_GRID = (N_NODES * DIM + 255) / 256;  // 25000

    // L1: mm(x)->A, agg(A)->out
    mm_kernel<<<MM_GRID, 256, 0, stream>>>(x, W[0], A);
    agg_kernel<<<AGG_GRID, 256, 0, stream>>>(A, csr, offsets, dinv, b[0], out);
    // L2: mm(out)->out (in-place), agg(out)->A
    mm_kernel<<<MM_GRID, 256, 0, stream>>>(out, W[1], out);
    agg_kernel<<<AGG_GRID, 256, 0, stream>>>(out, csr, offsets, dinv, b[1], A);
    // L3: mm(A)->A (in-place), agg(A)->out
    mm_kernel<<<MM_GRID, 256, 0, stream>>>(A, W[2], A);
    agg_kernel<<<AGG_GRID, 256, 0, stream>>>(A, csr, offsets, dinv, b[2], out);
    // L4: mm(out)->A, agg(A)->out
    mm_kernel<<<MM_GRID, 256, 0, stream>>>(out, W[3], A);
    agg_kernel<<<AGG_GRID, 256, 0, stream>>>(A, csr, offsets, dinv, b[3], out);
}

// Round 2
// 583.168 us; speedup vs baseline: 1.5577x; 1.5577x over previous
//
#include <hip/hip_runtime.h>

#define N_NODES 100000
#define N_EDGES 1600000
#define DIM 64
#define NEG_SLOPE 0.01f

// ---------------- histogram of dst (in-degree, excl self-loop) ----------------
__global__ void hist_kernel(const int* __restrict__ dst, int* __restrict__ counts) {
    int e = blockIdx.x * blockDim.x + threadIdx.x;
    if (e < N_EDGES) atomicAdd(&counts[dst[e]], 1);
}

// ---------------- 3-phase exclusive scan over counts[N] ----------------
__global__ void scan_partial(const int* __restrict__ counts, int* __restrict__ bsums) {
    __shared__ int sm[1024];
    int i = blockIdx.x * 1024 + threadIdx.x;
    int v = (i < N_NODES) ? counts[i] : 0;
    sm[threadIdx.x] = v;
    __syncthreads();
    for (int s = 512; s > 0; s >>= 1) {
        if (threadIdx.x < s) sm[threadIdx.x] += sm[threadIdx.x + s];
        __syncthreads();
    }
    if (threadIdx.x == 0) bsums[blockIdx.x] = sm[0];
}

__global__ void scan_bsums(int* __restrict__ bsums, int nb) {
    __shared__ int sm[128];
    if ((int)threadIdx.x < nb) sm[threadIdx.x] = bsums[threadIdx.x];
    __syncthreads();
    if (threadIdx.x == 0) {
        int run = 0;
        for (int b = 0; b < nb; ++b) { int t = sm[b]; sm[b] = run; run += t; }
    }
    __syncthreads();
    if ((int)threadIdx.x < nb) bsums[threadIdx.x] = sm[threadIdx.x];
}

__global__ void scan_final(const int* __restrict__ counts, const int* __restrict__ bsums,
                           int* __restrict__ offsets, float* __restrict__ dinv) {
    __shared__ int sm[1024];
    int i = blockIdx.x * 1024 + threadIdx.x;
    int v = (i < N_NODES) ? counts[i] : 0;
    sm[threadIdx.x] = v;
    __syncthreads();
    for (int s = 1; s < 1024; s <<= 1) {
        int add = ((int)threadIdx.x >= s) ? sm[threadIdx.x - s] : 0;
        __syncthreads();
        sm[threadIdx.x] += add;
        __syncthreads();
    }
    int incl = sm[threadIdx.x];
    if (i < N_NODES) {
        offsets[i] = bsums[blockIdx.x] + (incl - v);
        dinv[i] = rsqrtf((float)(v + 1));   // deg includes self-loop
    }
    if (i == 0) offsets[N_NODES] = N_EDGES;
}

// ---------------- CSR fill: group edges by dst, precompute coef ----------------
__global__ void fill_csr(const int* __restrict__ src, const int* __restrict__ dst,
                         const int* __restrict__ offsets, int* __restrict__ cursor,
                         const float* __restrict__ dinv, int2* __restrict__ csr) {
    int e = blockIdx.x * blockDim.x + threadIdx.x;
    if (e >= N_EDGES) return;
    int s = src[e], d = dst[e];
    int pos = offsets[d] + atomicAdd(&cursor[d], 1);
    float c = dinv[s] * dinv[d];
    csr[pos] = make_int2(s, __float_as_int(c));
}

// ---------------- fp32 matmul: T[i,:] = X[i,:] @ W (64x64) ----------------
// Block = 256 threads handles 64 rows. In-place safe (stages its 64 rows to LDS
// behind a barrier before any store).
__global__ __launch_bounds__(256) void mm_kernel(const float* X, const float* __restrict__ W,
                                                 float* T) {
    __shared__ float xs[64][68];   // +4 pad: r-groups land on distinct banks
    __shared__ float ws[64][64];
    const int t = threadIdx.x;
    const int rbase = blockIdx.x * 64;

    const float4* Wv = (const float4*)W;
    for (int i = t; i < 1024; i += 256)
        ((float4*)&ws[0][0])[i] = Wv[i];

    for (int i = t; i < 1024; i += 256) {
        int r = i >> 4, kb = i & 15;
        int row = rbase + r;
        float4 xv = make_float4(0.f, 0.f, 0.f, 0.f);
        if (row < N_NODES) xv = *(const float4*)(X + row * DIM + kb * 4);
        *(float4*)&xs[r][kb * 4] = xv;
    }
    __syncthreads();

    const int c4 = (t & 15) * 4;
    const int r0 = t >> 4;
    float4 a0 = make_float4(0.f, 0.f, 0.f, 0.f), a1 = a0, a2 = a0, a3 = a0;

#pragma unroll 4
    for (int kb = 0; kb < 16; ++kb) {
        float x0[4], x1[4], x2[4], x3[4];
        *(float4*)x0 = *(const float4*)&xs[r0][kb * 4];
        *(float4*)x1 = *(const float4*)&xs[r0 + 16][kb * 4];
        *(float4*)x2 = *(const float4*)&xs[r0 + 32][kb * 4];
        *(float4*)x3 = *(const float4*)&xs[r0 + 48][kb * 4];
#pragma unroll
        for (int j = 0; j < 4; ++j) {
            float4 wv = *(const float4*)&ws[kb * 4 + j][c4];
            a0.x = fmaf(x0[j], wv.x, a0.x); a0.y = fmaf(x0[j], wv.y, a0.y);
            a0.z = fmaf(x0[j], wv.z, a0.z); a0.w = fmaf(x0[j], wv.w, a0.w);
            a1.x = fmaf(x1[j], wv.x, a1.x); a1.y = fmaf(x1[j], wv.y, a1.y);
            a1.z = fmaf(x1[j], wv.z, a1.z); a1.w = fmaf(x1[j], wv.w, a1.w);
            a2.x = fmaf(x2[j], wv.x, a2.x); a2.y = fmaf(x2[j], wv.y, a2.y);
            a2.z = fmaf(x2[j], wv.z, a2.z); a2.w = fmaf(x2[j], wv.w, a2.w);
            a3.x = fmaf(x3[j], wv.x, a3.x); a3.y = fmaf(x3[j], wv.y, a3.y);
            a3.z = fmaf(x3[j], wv.z, a3.z); a3.w = fmaf(x3[j], wv.w, a3.w);
        }
    }

    int row;
    row = rbase + r0;      if (row < N_NODES) *(float4*)(T + row * DIM + c4) = a0;
    row = rbase + r0 + 16; if (row < N_NODES) *(float4*)(T + row * DIM + c4) = a1;
    row = rbase + r0 + 32; if (row < N_NODES) *(float4*)(T + row * DIM + c4) = a2;
    row = rbase + r0 + 48; if (row < N_NODES) *(float4*)(T + row * DIM + c4) = a3;
}

// ---------------- aggregate: wave per node, 4 edges in flight ----------------
// lane layout: slot = lane>>4 (4 edge slots), fc = (lane&15)*4 (float4 feature
// chunk). Each iteration gathers 4 rows (one per slot) as float4 per lane ->
// 4x memory-level parallelism vs lane-per-feature. Cross-slot reduction via
// shfl_xor(16), shfl_xor(32).
__global__ __launch_bounds__(256) void agg_kernel(const float* __restrict__ T,
                                                  const int2* __restrict__ csr,
                                                  const int* __restrict__ offsets,
                                                  const float* __restrict__ dinv,
                                                  const float* __restrict__ bias,
                                                  float* __restrict__ out) {
    int wid = (blockIdx.x * 256 + threadIdx.x) >> 6;   // node id
    if (wid >= N_NODES) return;
    const int lane = threadIdx.x & 63;
    const int slot = lane >> 4;          // 0..3
    const int fc   = (lane & 15) * 4;    // feature chunk base

    const int beg = offsets[wid], end = offsets[wid + 1];
    float4 acc = make_float4(0.f, 0.f, 0.f, 0.f);

    for (int e = beg + slot; e < end; e += 4) {
        int2 p = csr[e];
        float c = __int_as_float(p.y);
        float4 v = *(const float4*)(T + (size_t)p.x * DIM + fc);
        acc.x = fmaf(c, v.x, acc.x);
        acc.y = fmaf(c, v.y, acc.y);
        acc.z = fmaf(c, v.z, acc.z);
        acc.w = fmaf(c, v.w, acc.w);
    }

    // reduce the 4 slots (lanes fc_group + {0,16,32,48})
    acc.x += __shfl_xor(acc.x, 16, 64);
    acc.y += __shfl_xor(acc.y, 16, 64);
    acc.z += __shfl_xor(acc.z, 16, 64);
    acc.w += __shfl_xor(acc.w, 16, 64);
    acc.x += __shfl_xor(acc.x, 32, 64);
    acc.y += __shfl_xor(acc.y, 32, 64);
    acc.z += __shfl_xor(acc.z, 32, 64);
    acc.w += __shfl_xor(acc.w, 32, 64);

    if (slot == 0) {
        float di = dinv[wid];
        float dii = di * di;
        float4 h  = *(const float4*)(T + (size_t)wid * DIM + fc);
        float4 bv = *(const float4*)(bias + fc);
        float4 r;
        r.x = acc.x + dii * h.x + bv.x;
        r.y = acc.y + dii * h.y + bv.y;
        r.z = acc.z + dii * h.z + bv.z;
        r.w = acc.w + dii * h.w + bv.w;
        r.x = (r.x >= 0.f) ? r.x : NEG_SLOPE * r.x;
        r.y = (r.y >= 0.f) ? r.y : NEG_SLOPE * r.y;
        r.z = (r.z >= 0.f) ? r.z : NEG_SLOPE * r.z;
        r.w = (r.w >= 0.f) ? r.w : NEG_SLOPE * r.w;
        *(float4*)(out + (size_t)wid * DIM + fc) = r;
    }
}

extern "C" void kernel_launch(void* const* d_in, const int* in_sizes, int n_in,
                              void* d_out, int out_size, void* d_ws, size_t ws_size,
                              hipStream_t stream) {
    const float* x = (const float*)d_in[0];
    const int* ei = (const int*)d_in[1];
    const int* src = ei;
    const int* dst = ei + N_EDGES;
    const float* W[4] = {(const float*)d_in[2], (const float*)d_in[4],
                         (const float*)d_in[6], (const float*)d_in[8]};
    const float* b[4] = {(const float*)d_in[3], (const float*)d_in[5],
                         (const float*)d_in[7], (const float*)d_in[9]};
    float* out = (float*)d_out;

    char* ws = (char*)d_ws;
    size_t off = 0;
    auto alloc = [&](size_t bytes) -> void* {
        void* p = ws + off;
        off = (off + bytes + 255) & ~(size_t)255;
        return p;
    };
    float* A      = (float*)alloc((size_t)N_NODES * DIM * sizeof(float));
    int2*  csr    = (int2*)alloc((size_t)N_EDGES * sizeof(int2));
    int*   counts = (int*)alloc((size_t)N_NODES * sizeof(int));
    int*   cursor = (int*)alloc((size_t)N_NODES * sizeof(int));
    int*   offsets= (int*)alloc((size_t)(N_NODES + 1) * sizeof(int));
    float* dinv   = (float*)alloc((size_t)N_NODES * sizeof(float));
    int*   bsums  = (int*)alloc(128 * sizeof(int));

    const int NB = (N_NODES + 1023) / 1024;   // 98

    hipMemsetAsync(counts, 0, (size_t)N_NODES * sizeof(int), stream);
    hipMemsetAsync(cursor, 0, (size_t)N_NODES * sizeof(int), stream);

    hist_kernel<<<(N_EDGES + 255) / 256, 256, 0, stream>>>(dst, counts);
    scan_partial<<<NB, 1024, 0, stream>>>(counts, bsums);
    scan_bsums<<<1, 128, 0, stream>>>(bsums, NB);
    scan_final<<<NB, 1024, 0, stream>>>(counts, bsums, offsets, dinv);
    fill_csr<<<(N_EDGES + 255) / 256, 256, 0, stream>>>(src, dst, offsets, cursor, dinv, csr);

    const int MM_GRID  = (N_NODES + 63) / 64;          // 1563
    const int AGG_GRID = (N_NODES * DIM + 255) / 256;  // 25000

    // L1: mm(x)->A, agg(A)->out
    mm_kernel<<<MM_GRID, 256, 0, stream>>>(x, W[0], A);
    agg_kernel<<<AGG_GRID, 256, 0, stream>>>(A, csr, offsets, dinv, b[0], out);
    // L2: mm(out)->out (in-place), agg(out)->A
    mm_kernel<<<MM_GRID, 256, 0, stream>>>(out, W[1], out);
    agg_kernel<<<AGG_GRID, 256, 0, stream>>>(out, csr, offsets, dinv, b[1], A);
    // L3: mm(A)->A (in-place), agg(A)->out
    mm_kernel<<<MM_GRID, 256, 0, stream>>>(A, W[2], A);
    agg_kernel<<<AGG_GRID, 256, 0, stream>>>(A, csr, offsets, dinv, b[2], out);
    // L4: mm(out)->A, agg(A)->out
    mm_kernel<<<MM_GRID, 256, 0, stream>>>(out, W[3], A);
    agg_kernel<<<AGG_GRID, 256, 0, stream>>>(A, csr, offsets, dinv, b[3], out);
}